// Round 11
// baseline (435.545 us; speedup 1.0000x reference)
//
#include <hip/hip_runtime.h>
#include <hip/hip_fp16.h>

#define NEG_SLOPE 0.2f
#define H_IN 64

typedef _Float16 h2vec __attribute__((ext_vector_type(2)));

__device__ __forceinline__ float lrelu(float v) { return v > 0.f ? v : NEG_SLOPE * v; }

__device__ __forceinline__ void cvt4(uint2 g, float* o) {
    __half2 lo = *(__half2*)&g.x, hi = *(__half2*)&g.y;
    float2 a = __half22float2(lo), b = __half22float2(hi);
    o[0] = a.x; o[1] = a.y; o[2] = b.x; o[3] = b.y;
}

__device__ __forceinline__ float fdot2h(float xf, h2vec w, float acc) {
#if __has_builtin(__builtin_amdgcn_fdot2)
    union { float f; h2vec h; } cv; cv.f = xf;
    return __builtin_amdgcn_fdot2(cv.h, w, acc, false);
#else
    union { float f; __half2 h; } cv; cv.f = xf;
    float2 g = __half22float2(cv.h);
    acc = fmaf(g.x, (float)w[0], acc);
    return fmaf(g.y, (float)w[1], acc);
#endif
}

#define NEG_BIG -1e30f

// online (max,sum) lane-combine over the wave; no NaNs since lm >= NEG_BIG
__device__ __forceinline__ void wave_online(float& lm, float& ls) {
    #pragma unroll
    for (int off = 32; off; off >>= 1) {
        float om = __shfl_xor(lm, off), os = __shfl_xor(ls, off);
        float M = fmaxf(lm, om);
        ls = ls * __expf(lm - M) + os * __expf(om - M);
        lm = M;
    }
}

// ---------------------------------------------------------------------------
// zero + micro fused: blocks 1..NB zero deg; block 0 computes W·att.
// ---------------------------------------------------------------------------
__global__ __launch_bounds__(256) void zero_micro(
    int* __restrict__ deg, int n,
    const float* __restrict__ W1, const float* __restrict__ as1, const float* __restrict__ ad1,
    const float* __restrict__ W2, const float* __restrict__ as2, const float* __restrict__ ad2,
    float* __restrict__ wa1s, float* __restrict__ wa1d,
    float* __restrict__ wa2s, float* __restrict__ wa2d)
{
    int tid = threadIdx.x;
    if (blockIdx.x > 0) {
        int i = (blockIdx.x - 1) * 256 + tid;
        if (i < n) deg[i] = 0;
        return;
    }
    int k = tid >> 2, h = tid & 3;
    float s = 0.f, d = 0.f;
    #pragma unroll 8
    for (int c = 0; c < 64; ++c) {
        float w = W1[k * 256 + h * 64 + c];
        s = fmaf(w, as1[h * 64 + c], s);
        d = fmaf(w, ad1[h * 64 + c], d);
    }
    wa1s[k * 4 + h] = s; wa1d[k * 4 + h] = d;
    float s2 = 0.f, d2 = 0.f;
    #pragma unroll 8
    for (int c = 0; c < 64; ++c) {
        float w = W2[tid * 64 + c];
        s2 = fmaf(w, as2[c], s2);
        d2 = fmaf(w, ad2[c], d2);
    }
    wa2s[tid] = s2; wa2d[tid] = d2;
}

__global__ __launch_bounds__(256) void hist_kernel(const int* __restrict__ dst,
                                                   int* __restrict__ deg, int ne)
{
    int e = (blockIdx.x * 256 + threadIdx.x) * 2;
    if (e + 1 < ne) {
        int2 dd = *(const int2*)(dst + e);
        atomicAdd(&deg[dd.x], 1);
        atomicAdd(&deg[dd.y], 1);
    } else if (e < ne) {
        atomicAdd(&deg[dst[e]], 1);
    }
}

__global__ __launch_bounds__(256) void block_sum(const int* __restrict__ deg,
                                                 int* __restrict__ bsum, int n)
{
    __shared__ int part[4];
    int i = blockIdx.x * 256 + threadIdx.x;
    int v = (i < n) ? deg[i] : 0;
    #pragma unroll
    for (int off = 32; off; off >>= 1) v += __shfl_down(v, off);
    int lane = threadIdx.x & 63, wv = threadIdx.x >> 6;
    if (lane == 0) part[wv] = v;
    __syncthreads();
    if (threadIdx.x == 0)
        bsum[blockIdx.x] = part[0] + part[1] + part[2] + part[3];
}

__global__ __launch_bounds__(256) void scan_bsum(const int* __restrict__ bsum,
                                                 int* __restrict__ bpre, int nb)
{
    __shared__ int sm[256];
    int t = threadIdx.x;
    int v = (t < nb) ? bsum[t] : 0;
    sm[t] = v; __syncthreads();
    for (int off = 1; off < 256; off <<= 1) {
        int y = (t >= off) ? sm[t - off] : 0;
        __syncthreads();
        if (t >= off) sm[t] += y;
        __syncthreads();
    }
    if (t < nb) bpre[t] = sm[t] - v;   // exclusive
}

__global__ __launch_bounds__(256) void scan_rowptr(const int* __restrict__ deg,
                                                   const int* __restrict__ bpre,
                                                   int* __restrict__ rowptr,
                                                   int* __restrict__ cursor, int n)
{
    __shared__ int sm[256];
    int t = threadIdx.x;
    int i = blockIdx.x * 256 + t;
    int v = (i < n) ? deg[i] : 0;
    sm[t] = v; __syncthreads();
    for (int off = 1; off < 256; off <<= 1) {
        int y = (t >= off) ? sm[t - off] : 0;
        __syncthreads();
        if (t >= off) sm[t] += y;
        __syncthreads();
    }
    if (i < n) {
        int rp = sm[t] - v + bpre[blockIdx.x];
        rowptr[i] = rp;
        cursor[i] = rp;                 // scatter's write cursor starts at rowptr
    }
}

__global__ __launch_bounds__(256) void scatter_kernel(
    const int* __restrict__ src, const int* __restrict__ dst,
    int* __restrict__ cursor, int* __restrict__ csr_src, int ne)
{
    int e = (blockIdx.x * 256 + threadIdx.x) * 2;
    if (e + 1 < ne) {
        int2 sv = *(const int2*)(src + e);
        int2 dv = *(const int2*)(dst + e);
        csr_src[atomicAdd(&cursor[dv.x], 1)] = sv.x;
        csr_src[atomicAdd(&cursor[dv.y], 1)] = sv.y;
    } else if (e < ne) {
        csr_src[atomicAdd(&cursor[dst[e]], 1)] = src[e];
    }
}

// ---------------------------------------------------------------------------
// axw1: a_s1[row,h] = sum_k x[row,k]*wa1s[k,h]  (and a_d1)
// ---------------------------------------------------------------------------
__global__ __launch_bounds__(256) void axw1_kernel(
    const float* __restrict__ x,
    const float* __restrict__ wa1s, const float* __restrict__ wa1d,
    float* __restrict__ a_s, float* __restrict__ a_d, int n)
{
    __shared__ float ws[256], wd[256];
    int tid = threadIdx.x;
    ws[tid] = wa1s[tid]; wd[tid] = wa1d[tid];
    __syncthreads();
    int row = blockIdx.x * 256 + tid;
    if (row >= n) return;
    const float4* xv = (const float4*)(x + (size_t)row * 64);
    float aS[4] = {0, 0, 0, 0}, aD[4] = {0, 0, 0, 0};
    #pragma unroll
    for (int k4 = 0; k4 < 16; ++k4) {
        float4 q = xv[k4];
        float xe[4] = {q.x, q.y, q.z, q.w};
        #pragma unroll
        for (int e = 0; e < 4; ++e) {
            int k = k4 * 4 + e;
            #pragma unroll
            for (int h = 0; h < 4; ++h) {
                aS[h] = fmaf(xe[e], ws[k * 4 + h], aS[h]);
                aD[h] = fmaf(xe[e], wd[k * 4 + h], aD[h]);
            }
        }
    }
    #pragma unroll
    for (int h = 0; h < 4; ++h) {
        a_s[row * 4 + h] = aS[h];
        a_d[row * 4 + h] = aD[h];
    }
}

// ---------------------------------------------------------------------------
// gemm1: h1[N,256] (fp16) = x[N,64] @ W1[64,256]; 16 rows/block, acc[16]/thread.
// ---------------------------------------------------------------------------
__global__ __launch_bounds__(256) void gemm1_kernel(
    const float* __restrict__ x, const float* __restrict__ W1,
    __half* __restrict__ h1, int n)
{
    __shared__ float w_s[32 * 256];          // 32 KB
    int tid = threadIdx.x;
    int row0 = blockIdx.x * 16;              // n divisible by 16
    float acc[16];
    #pragma unroll
    for (int r = 0; r < 16; ++r) acc[r] = 0.f;

    const float4* Wv = (const float4*)W1;
    for (int kk = 0; kk < 2; ++kk) {
        if (kk) __syncthreads();
        {
            float4* wv = (float4*)w_s;
            #pragma unroll
            for (int i = 0; i < 8; ++i)
                wv[tid + i * 256] = Wv[kk * 2048 + tid + i * 256];
        }
        __syncthreads();
        #pragma unroll 2
        for (int k4 = 0; k4 < 8; ++k4) {
            float4 q[16];
            #pragma unroll
            for (int r = 0; r < 16; ++r)
                q[r] = *(const float4*)(x + (size_t)(row0 + r) * 64 + kk * 32 + k4 * 4);
            #pragma unroll
            for (int e = 0; e < 4; ++e) {
                float w = w_s[(k4 * 4 + e) * 256 + tid];
                #pragma unroll
                for (int r = 0; r < 16; ++r)
                    acc[r] = fmaf(((const float*)&q[r])[e], w, acc[r]);
            }
        }
    }
    #pragma unroll
    for (int r = 0; r < 16; ++r)
        h1[(size_t)(row0 + r) * 256 + tid] = __float2half(acc[r]);
}

// ---------------------------------------------------------------------------
// gemm2: h2[N,64] (fp16) = out1r[N,256] (fp16) @ W2[256,64]; 64 rows/block
// (16/wave). Entire W2 packed fp16 in 32KB LDS; v_dot2_f32_f16 inner loop.
// ---------------------------------------------------------------------------
__global__ __launch_bounds__(256) void gemm2_kernel(
    const __half* __restrict__ xr, const float* __restrict__ W2,
    __half* __restrict__ h2, int n)
{
    __shared__ h2vec w_s[128 * 64];          // 32 KB
    int tid = threadIdx.x;
    #pragma unroll 4
    for (int i = 0; i < 32; ++i) {
        int idx = tid + i * 256;
        int kp = idx >> 6, col = idx & 63;
        h2vec v;
        v[0] = (_Float16)W2[(2 * kp) * 64 + col];
        v[1] = (_Float16)W2[(2 * kp + 1) * 64 + col];
        w_s[idx] = v;
    }
    __syncthreads();
    int col = tid & 63, wv_ = tid >> 6;
    int row0 = blockIdx.x * 64 + wv_ * 16;
    float acc[16];
    #pragma unroll
    for (int r = 0; r < 16; ++r) acc[r] = 0.f;

    const float4* xb = (const float4*)(xr + (size_t)row0 * 256);  // row = 32 float4
    for (int g = 0; g < 32; ++g) {
        float4 q[16];
        #pragma unroll
        for (int r = 0; r < 16; ++r) q[r] = xb[r * 32 + g];
        #pragma unroll
        for (int e = 0; e < 4; ++e) {
            h2vec w = w_s[(g * 4 + e) * 64 + col];
            #pragma unroll
            for (int r = 0; r < 16; ++r)
                acc[r] = fdot2h(((const float*)&q[r])[e], w, acc[r]);
        }
    }
    #pragma unroll
    for (int r = 0; r < 16; ++r) {
        int row = row0 + r;
        if (row < n) h2[(size_t)row * 64 + col] = __float2half(acc[r]);
    }
}

// ---------------------------------------------------------------------------
// fused layer-1: ONE-PASS online softmax + aggregate + bias + relu + L2 logits.
// one block per dst node; softmax wave == head; gather: c4=tid&63 channel quad,
// p=tid>>6 edge slot. al padded [4][68], pm padded [..][5] (bank-conflict-free).
// ---------------------------------------------------------------------------
__global__ __launch_bounds__(256) void aggr1_csr(
    const int* __restrict__ rowptr, const int* __restrict__ deg,
    const int* __restrict__ csr_src,
    const float* __restrict__ a_s, const float* __restrict__ a_d,
    const __half* __restrict__ h1, const float* __restrict__ b1,
    const float* __restrict__ wa2s, const float* __restrict__ wa2d,
    __half* __restrict__ out1r, float* __restrict__ a_s2, float* __restrict__ a_d2,
    int n)
{
    __shared__ float al[4][68];
    __shared__ int   ss[64];
    __shared__ float ev[4][128];
    __shared__ float pm[3][64][5];
    int t = blockIdx.x;
    int tid = threadIdx.x, h = tid >> 6, lane = tid & 63;
    int row0 = rowptr[t], d = deg[t];
    float adt = a_d[t * 4 + h];
    bool small = (d <= 128);

    // ---- single-pass online softmax (running max lm, rescaled sum ls) ----
    float lm = NEG_BIG, ls = 0.f;
    if (small) {
        for (int i = lane; i < d; i += 64) {
            float v = lrelu(a_s[csr_src[row0 + i] * 4 + h] + adt);
            ev[h][i] = v;
            float M = fmaxf(lm, v);
            ls = ls * __expf(lm - M) + __expf(v - M);
            lm = M;
        }
    } else {
        for (int i = lane; i < d; i += 64) {
            float v = lrelu(a_s[csr_src[row0 + i] * 4 + h] + adt);
            float M = fmaxf(lm, v);
            ls = ls * __expf(lm - M) + __expf(v - M);
            lm = M;
        }
    }
    wave_online(lm, ls);
    float inv = (d > 0) ? 1.f / ls : 0.f;

    int c4 = tid & 63;           // channel quad: halves [4*c4 .. 4*c4+3]
    int p = tid >> 6;            // edge slot 0..3
    int hc = c4 >> 4;            // head of these channels
    float acc[4] = {0.f, 0.f, 0.f, 0.f};
    const uint2* hb = (const uint2*)h1;     // row = 64 uint2

    for (int c0 = 0; c0 < d; c0 += 64) {
        int i = c0 + lane;
        float alpha = 0.f;
        if (i < d) {
            float v = small ? ev[h][i] : lrelu(a_s[csr_src[row0 + i] * 4 + h] + adt);
            alpha = __expf(v - lm) * inv;
        }
        al[h][lane] = alpha;
        if (h == 0) ss[lane] = (i < d) ? csr_src[row0 + i] * 64 : 0;
        __syncthreads();
        int cl = min(64, d - c0);
        int j = p;
        for (; j + 4 < cl; j += 8) {
            float a0 = al[hc][j], a1 = al[hc][j + 4];
            uint2 g0 = hb[ss[j] + c4];
            uint2 g1 = hb[ss[j + 4] + c4];
            float f0[4], f1[4];
            cvt4(g0, f0); cvt4(g1, f1);
            #pragma unroll
            for (int q = 0; q < 4; ++q) {
                acc[q] = fmaf(a0, f0[q], acc[q]);
                acc[q] = fmaf(a1, f1[q], acc[q]);
            }
        }
        if (j < cl) {
            float a0 = al[hc][j];
            uint2 g0 = hb[ss[j] + c4];
            float f0[4];
            cvt4(g0, f0);
            #pragma unroll
            for (int q = 0; q < 4; ++q) acc[q] = fmaf(a0, f0[q], acc[q]);
        }
        __syncthreads();
    }

    if (p) {
        #pragma unroll
        for (int q = 0; q < 4; ++q) pm[p - 1][c4][q] = acc[q];
    }
    __syncthreads();
    if (p == 0) {                            // wave 0
        float4 bb = ((const float4*)b1)[c4];
        float r0 = fmaxf(acc[0] + pm[0][c4][0] + pm[1][c4][0] + pm[2][c4][0] + bb.x, 0.f);
        float r1 = fmaxf(acc[1] + pm[0][c4][1] + pm[1][c4][1] + pm[2][c4][1] + bb.y, 0.f);
        float r2 = fmaxf(acc[2] + pm[0][c4][2] + pm[1][c4][2] + pm[2][c4][2] + bb.z, 0.f);
        float r3 = fmaxf(acc[3] + pm[0][c4][3] + pm[1][c4][3] + pm[2][c4][3] + bb.w, 0.f);
        __half2 lo = __floats2half2_rn(r0, r1), hi = __floats2half2_rn(r2, r3);
        uint2 o; o.x = *(unsigned*)&lo; o.y = *(unsigned*)&hi;
        ((uint2*)out1r)[(size_t)t * 64 + c4] = o;
        float4 ws4 = ((const float4*)wa2s)[c4];
        float4 wd4 = ((const float4*)wa2d)[c4];
        float s2  = r0 * ws4.x + r1 * ws4.y + r2 * ws4.z + r3 * ws4.w;
        float d2v = r0 * wd4.x + r1 * wd4.y + r2 * wd4.z + r3 * wd4.w;
        #pragma unroll
        for (int off = 32; off; off >>= 1) {
            s2  += __shfl_down(s2, off);
            d2v += __shfl_down(d2v, off);
        }
        if (tid == 0) { a_s2[t] = s2; a_d2[t] = d2v; }
    }
}

// ---------------------------------------------------------------------------
// fused layer-2: ONE-PASS online softmax + aggregate. one wave per dst node
// (4/block); lanes 0-15 channel quads, lane>>4 = edge slot.
// ---------------------------------------------------------------------------
__global__ __launch_bounds__(256) void aggr2_csr(
    const int* __restrict__ rowptr, const int* __restrict__ deg,
    const int* __restrict__ csr_src,
    const float* __restrict__ a_s, const float* __restrict__ a_d,
    const __half* __restrict__ h2, const float* __restrict__ b2,
    float* __restrict__ dout, int n)
{
    __shared__ float ev2[4][128];
    __shared__ float al2[4][64];
    __shared__ int   ss2[4][64];
    int wv = threadIdx.x >> 6, lane = threadIdx.x & 63;
    int t = blockIdx.x * 4 + wv;
    if (t >= n) return;
    int row0 = rowptr[t], d = deg[t];
    float adt = a_d[t];
    bool small = (d <= 128);

    float lm = NEG_BIG, ls = 0.f;
    if (small) {
        for (int i = lane; i < d; i += 64) {
            float v = lrelu(a_s[csr_src[row0 + i]] + adt);
            ev2[wv][i] = v;
            float M = fmaxf(lm, v);
            ls = ls * __expf(lm - M) + __expf(v - M);
            lm = M;
        }
    } else {
        for (int i = lane; i < d; i += 64) {
            float v = lrelu(a_s[csr_src[row0 + i]] + adt);
            float M = fmaxf(lm, v);
            ls = ls * __expf(lm - M) + __expf(v - M);
            lm = M;
        }
    }
    wave_online(lm, ls);
    float inv = (d > 0) ? 1.f / ls : 0.f;

    int c4 = lane & 15;          // channel quad (row = 16 uint2)
    int p = lane >> 4;           // edge slot 0..3
    float acc[4] = {0.f, 0.f, 0.f, 0.f};
    const uint2* hb = (const uint2*)h2;

    for (int c0 = 0; c0 < d; c0 += 64) {
        int i = c0 + lane;
        float alpha = 0.f; int so = 0;
        if (i < d) {
            int s = csr_src[row0 + i];
            so = s * 16;
            float v = small ? ev2[wv][i] : lrelu(a_s[s] + adt);
            alpha = __expf(v - lm) * inv;
        }
        al2[wv][lane] = alpha;
        ss2[wv][lane] = so;
        int cl = min(64, d - c0);
        int j = p;
        for (; j + 4 < cl; j += 8) {
            float a0 = al2[wv][j], a1 = al2[wv][j + 4];
            uint2 g0 = hb[ss2[wv][j] + c4];
            uint2 g1 = hb[ss2[wv][j + 4] + c4];
            float f0[4], f1[4];
            cvt4(g0, f0); cvt4(g1, f1);
            #pragma unroll
            for (int q = 0; q < 4; ++q) {
                acc[q] = fmaf(a0, f0[q], acc[q]);
                acc[q] = fmaf(a1, f1[q], acc[q]);
            }
        }
        if (j < cl) {
            float a0 = al2[wv][j];
            uint2 g0 = hb[ss2[wv][j] + c4];
            float f0[4];
            cvt4(g0, f0);
            #pragma unroll
            for (int q = 0; q < 4; ++q) acc[q] = fmaf(a0, f0[q], acc[q]);
        }
    }

    #pragma unroll
    for (int q = 0; q < 4; ++q) {
        acc[q] += __shfl_down(acc[q], 32);
        acc[q] += __shfl_down(acc[q], 16);
    }
    if (p == 0) {
        float4 bb = ((const float4*)b2)[c4];
        float4 o;
        o.x = acc[0] + bb.x; o.y = acc[1] + bb.y;
        o.z = acc[2] + bb.z; o.w = acc[3] + bb.w;
        ((float4*)(dout + (size_t)t * 64))[c4] = o;
    }
}

// ---------------------------------------------------------------------------
extern "C" void kernel_launch(void* const* d_in, const int* in_sizes, int n_in,
                              void* d_out, int out_size, void* d_ws, size_t ws_size,
                              hipStream_t stream)
{
    const float* x    = (const float*)d_in[0];
    const int*   ei   = (const int*)d_in[1];
    const float* W1   = (const float*)d_in[2];
    const float* as1  = (const float*)d_in[3];
    const float* ad1  = (const float*)d_in[4];
    const float* b1   = (const float*)d_in[5];
    const float* W2   = (const float*)d_in[6];
    const float* as2  = (const float*)d_in[7];
    const float* ad2  = (const float*)d_in[8];
    const float* b2   = (const float*)d_in[9];
    float* dout = (float*)d_out;

    const int n  = in_sizes[0] / H_IN;        // 50000
    const int ne = in_sizes[1] / 2;           // 800000
    const int* src = ei;
    const int* dst = ei + ne;
    const int NB = (n + 255) / 256;           // 196

    float* ws = (float*)d_ws;
    __half* h1h   = (__half*)ws;                    // n*256 halves; reused as h2
    __half* out1r = h1h + (size_t)n * 256;          // n*256 halves
    float* fbase  = ws + (size_t)n * 256;           // after the two half arrays
    float* a_s1   = fbase;                          // n*4
    float* a_d1   = a_s1   + (size_t)n * 4;         // n*4
    float* a_s2   = a_d1   + (size_t)n * 4;         // n
    float* a_d2   = a_s2   + (size_t)n;             // n
    float* wa1s   = a_d2   + (size_t)n;             // 256
    float* wa1d   = wa1s + 256;                     // 256
    float* wa2s   = wa1d + 256;                     // 256
    float* wa2d   = wa2s + 256;                     // 256
    int*   deg    = (int*)(wa2d + 256);             // n
    int*   rowptr = deg + n;                        // n
    int*   csr    = rowptr + n;                     // ne
    int*   bsum   = csr + ne;                       // NB
    int*   bpre   = bsum + NB;                      // NB
    int*   cursor = (int*)h1h;                      // n ints (dead before gemm1 writes h1)
    __half* h2h   = h1h;                            // n*64 halves (h1 dead after aggr1)

    // ---- zero deg + micro (W·att) ----
    zero_micro<<<NB + 1, 256, 0, stream>>>(deg, n, W1, as1, ad1,
                                           W2, as2, ad2, wa1s, wa1d, wa2s, wa2d);

    // ---- CSR build ----
    hist_kernel<<<(ne / 2 + 255) / 256, 256, 0, stream>>>(dst, deg, ne);
    block_sum<<<NB, 256, 0, stream>>>(deg, bsum, n);
    scan_bsum<<<1, 256, 0, stream>>>(bsum, bpre, NB);
    scan_rowptr<<<NB, 256, 0, stream>>>(deg, bpre, rowptr, cursor, n);
    scatter_kernel<<<(ne / 2 + 255) / 256, 256, 0, stream>>>(src, dst, cursor, csr, ne);

    // ---- layer 1 ----
    axw1_kernel<<<NB, 256, 0, stream>>>(x, wa1s, wa1d, a_s1, a_d1, n);
    gemm1_kernel<<<n / 16, 256, 0, stream>>>(x, W1, h1h, n);
    aggr1_csr<<<n, 256, 0, stream>>>(rowptr, deg, csr, a_s1, a_d1, h1h, b1,
                                     wa2s, wa2d, out1r, a_s2, a_d2, n);

    // ---- layer 2 ----
    gemm2_kernel<<<(n + 63) / 64, 256, 0, stream>>>(out1r, W2, h2h, n);
    aggr2_csr<<<(n + 3) / 4, 256, 0, stream>>>(rowptr, deg, csr, a_s2, a_d2, h2h, b2, dout, n);
}